// Round 5
// baseline (977.420 us; speedup 1.0000x reference)
//
#include <hip/hip_runtime.h>
#include <hip/hip_bf16.h>

#define B_  4
#define T_  2048
#define D_  2048
#define H_  16
#define DH_ 128

typedef __attribute__((ext_vector_type(4))) float f32x4;
typedef __attribute__((ext_vector_type(8))) short short8;
typedef __attribute__((ext_vector_type(4))) _Float16 half4;

__device__ __forceinline__ ushort f2bf(float f) {
    unsigned int u = __builtin_bit_cast(unsigned int, f);
    u += 0x7fffu + ((u >> 16) & 1u);   // RNE
    return (ushort)(u >> 16);
}
__device__ __forceinline__ ushort f2h(float f) {
    return (ushort)(__builtin_bit_cast(unsigned int, __builtin_amdgcn_cvt_pkrtz(f, f)) & 0xffffu);
}

// async global -> LDS, 16B per lane. LDS dst must be wave-uniform base + lane*16.
__device__ __forceinline__ void glds16(const void* g, void* l) {
    __builtin_amdgcn_global_load_lds(
        (const __attribute__((address_space(1))) unsigned int*)g,
        (__attribute__((address_space(3))) unsigned int*)l, 16, 0, 0);
}

// ---------------------------------------------------------------- cast x -> bf16
__global__ void cast_f32_bf16(const float* __restrict__ x, ushort* __restrict__ xb, int n) {
    int i = (blockIdx.x * 256 + threadIdx.x) * 4;
    if (i < n) {
        float4 v = *(const float4*)(x + i);
        ushort4 o;
        o.x = f2bf(v.x); o.y = f2bf(v.y); o.z = f2bf(v.z); o.w = f2bf(v.w);
        *(ushort4*)(xb + i) = o;
    }
}

// ------------------------------------------------- 4x fused: W [k][n] fp32 -> Wt [n][k] bf16
__global__ void transpose_cast4(
    const float* __restrict__ W0, const float* __restrict__ W1,
    const float* __restrict__ W2, const float* __restrict__ W3,
    ushort* __restrict__ T0, ushort* __restrict__ T1,
    ushort* __restrict__ T2, ushort* __restrict__ T3)
{
    const int z = blockIdx.z;
    const float* W = (z == 0) ? W0 : (z == 1) ? W1 : (z == 2) ? W2 : W3;
    ushort* Wt     = (z == 0) ? T0 : (z == 1) ? T1 : (z == 2) ? T2 : T3;
    __shared__ float tile[32][33];
    int tx = threadIdx.x, ty = threadIdx.y;           // 32 x 8
    int n0 = blockIdx.x * 32, k0 = blockIdx.y * 32;
#pragma unroll
    for (int i = 0; i < 4; i++)
        tile[ty + i * 8][tx] = W[(size_t)(k0 + ty + i * 8) * D_ + n0 + tx];
    __syncthreads();
#pragma unroll
    for (int i = 0; i < 4; i++)
        Wt[(size_t)(n0 + ty + i * 8) * D_ + k0 + tx] = f2bf(tile[tx][ty + i * 8]);
}

// ---------------------------------------------------------------- merged QKV GEMM (128^2, proven)
__global__ __launch_bounds__(256, 3) void gemm_qkv(
    const ushort* __restrict__ A,
    const ushort* __restrict__ Wq, const ushort* __restrict__ Wk, const ushort* __restrict__ Wv,
    const float* __restrict__ bq, const float* __restrict__ bk, const float* __restrict__ bv,
    ushort* __restrict__ Qb, ushort* __restrict__ Kb, ushort* __restrict__ Vtb,
    float qscale)
{
    extern __shared__ char smem[];
    uint4* sA = (uint4*)smem;              // [128 rows][4 chunks], slot c holds chunk c^sw(row)
    uint4* sB = (uint4*)(smem + 8192);

    const int tid  = threadIdx.x;
    const int sel  = blockIdx.x >> 4;           // 0=Q 1=K 2=V
    const int row0 = blockIdx.y * 128, col0 = (blockIdx.x & 15) * 128;
    const ushort* Bt = (sel == 0) ? Wq : (sel == 1) ? Wk : Wv;
    const float* bias = (sel == 0) ? bq : (sel == 1) ? bk : bv;
    const float oscale = (sel == 0) ? qscale : 1.0f;
    const int K = D_, N = D_;

    const int mA = tid >> 2, g = tid & 3;
    const int gc = g ^ ((mA >> 2) & 3);
    const ushort* pa0 = A  + (size_t)(row0 + mA) * K + gc * 8;
    const ushort* pb0 = Bt + (size_t)(col0 + mA) * K + gc * 8;

    const int lane = tid & 63, w = tid >> 6;
    const int l15 = lane & 15, quad = lane >> 4;
    const int wm = w & 1, wn = w >> 1;
    const int csel = quad ^ ((l15 >> 2) & 3);
    int aoff[4], boff[4];
#pragma unroll
    for (int mt = 0; mt < 4; mt++) aoff[mt] = (wm * 64 + mt * 16 + l15) * 4 + csel;
#pragma unroll
    for (int nt = 0; nt < 4; nt++) boff[nt] = (wn * 64 + nt * 16 + l15) * 4 + csel;

    f32x4 acc[4][4] = {};

    const int kIter = K >> 5;
    for (int kt = 0; kt < kIter; ++kt) {
        if (kt) __syncthreads();
        glds16(pa0 + kt * 32,                     sA + tid);
        glds16(pa0 + kt * 32 + (size_t)64 * K,    sA + tid + 256);
        glds16(pb0 + kt * 32,                     sB + tid);
        glds16(pb0 + kt * 32 + (size_t)64 * K,    sB + tid + 256);
        __syncthreads();
        short8 af[4], bfr[4];
#pragma unroll
        for (int mt = 0; mt < 4; mt++) af[mt]  = __builtin_bit_cast(short8, sA[aoff[mt]]);
#pragma unroll
        for (int nt = 0; nt < 4; nt++) bfr[nt] = __builtin_bit_cast(short8, sB[boff[nt]]);
#pragma unroll
        for (int mt = 0; mt < 4; mt++)
#pragma unroll
            for (int nt = 0; nt < 4; nt++)
                acc[mt][nt] = __builtin_amdgcn_mfma_f32_16x16x32_bf16(af[mt], bfr[nt], acc[mt][nt], 0, 0, 0);
    }

    if (sel < 2) {
        ushort* Cout = (sel == 0) ? Qb : Kb;
#pragma unroll
        for (int nt = 0; nt < 4; nt++) {
            int col = col0 + wn * 64 + nt * 16 + l15;
            float bb = bias[col];
#pragma unroll
            for (int mt = 0; mt < 4; mt++) {
                int rowb = row0 + wm * 64 + mt * 16 + quad * 4;
#pragma unroll
                for (int r = 0; r < 4; ++r)
                    Cout[(size_t)(rowb + r) * N + col] = f2bf((acc[mt][nt][r] + bb) * oscale);
            }
        }
    } else {
        // V path: transpose 128x128 tile through LDS, emit f16 [B,H,DH,T]
        __syncthreads();
        ushort* tr = (ushort*)smem;        // [128 dh][136]
#pragma unroll
        for (int nt = 0; nt < 4; nt++) {
            int cl = wn * 64 + nt * 16 + l15;
            float bb = bias[col0 + cl];
#pragma unroll
            for (int mt = 0; mt < 4; mt++) {
                int rl = wm * 64 + mt * 16 + quad * 4;
#pragma unroll
                for (int r = 0; r < 4; ++r)
                    tr[cl * 136 + rl + r] = f2h(acc[mt][nt][r] + bb);
            }
        }
        __syncthreads();
        int b = row0 >> 11, t0 = row0 & (T_ - 1), h = col0 >> 7;
        for (int idx = tid; idx < 2048; idx += 256) {
            int dh = idx >> 4, c = idx & 15;
            uint4 v = *(const uint4*)(tr + dh * 136 + c * 8);
            *(uint4*)(Vtb + (size_t)((b * H_ + h) * DH_ + dh) * T_ + t0 + c * 8) = v;
        }
    }
}

// ---------------------------------------------------------------- O-projection GEMM (f32 out, proven)
__global__ __launch_bounds__(256, 3) void gemm_bt_f32(
    const ushort* __restrict__ A, const ushort* __restrict__ Bt,
    const float* __restrict__ bias, float* __restrict__ Cout,
    int M, int N, int K)
{
    extern __shared__ char smem[];
    uint4* sA = (uint4*)smem;
    uint4* sB = (uint4*)(smem + 8192);

    const int tid  = threadIdx.x;
    const int row0 = blockIdx.y * 128, col0 = blockIdx.x * 128;

    const int mA = tid >> 2, g = tid & 3;
    const int gc = g ^ ((mA >> 2) & 3);
    const ushort* pa0 = A  + (size_t)(row0 + mA) * K + gc * 8;
    const ushort* pb0 = Bt + (size_t)(col0 + mA) * K + gc * 8;

    const int lane = tid & 63, w = tid >> 6;
    const int l15 = lane & 15, quad = lane >> 4;
    const int wm = w & 1, wn = w >> 1;
    const int csel = quad ^ ((l15 >> 2) & 3);
    int aoff[4], boff[4];
#pragma unroll
    for (int mt = 0; mt < 4; mt++) aoff[mt] = (wm * 64 + mt * 16 + l15) * 4 + csel;
#pragma unroll
    for (int nt = 0; nt < 4; nt++) boff[nt] = (wn * 64 + nt * 16 + l15) * 4 + csel;

    f32x4 acc[4][4] = {};

    const int kIter = K >> 5;
    for (int kt = 0; kt < kIter; ++kt) {
        if (kt) __syncthreads();
        glds16(pa0 + kt * 32,                     sA + tid);
        glds16(pa0 + kt * 32 + (size_t)64 * K,    sA + tid + 256);
        glds16(pb0 + kt * 32,                     sB + tid);
        glds16(pb0 + kt * 32 + (size_t)64 * K,    sB + tid + 256);
        __syncthreads();
        short8 af[4], bfr[4];
#pragma unroll
        for (int mt = 0; mt < 4; mt++) af[mt]  = __builtin_bit_cast(short8, sA[aoff[mt]]);
#pragma unroll
        for (int nt = 0; nt < 4; nt++) bfr[nt] = __builtin_bit_cast(short8, sB[boff[nt]]);
#pragma unroll
        for (int mt = 0; mt < 4; mt++)
#pragma unroll
            for (int nt = 0; nt < 4; nt++)
                acc[mt][nt] = __builtin_amdgcn_mfma_f32_16x16x32_bf16(af[mt], bfr[nt], acc[mt][nt], 0, 0, 0);
    }

#pragma unroll
    for (int nt = 0; nt < 4; nt++) {
        int col = col0 + wn * 64 + nt * 16 + l15;
        float bb = bias[col];
#pragma unroll
        for (int mt = 0; mt < 4; mt++) {
            int rowb = row0 + wm * 64 + mt * 16 + quad * 4;
#pragma unroll
            for (int r = 0; r < 4; ++r)
                Cout[(size_t)(rowb + r) * N + col] = acc[mt][nt][r] + bb;
        }
    }
}

// ---------------------------------------------------------------- flash attention (S^T / O^T form)
// Q (pre-scaled by 1/sqrt(DH)*log2e), K: [B,T,D] bf16 ; Vt: [B,H,DH,T] f16 ; O: [B,T,D] bf16
// R4: the block's TWO q-tiles (qx and 31-qx) are processed in ONE merged pass over K/V:
// per staged K/V tile i, compute QK^T/softmax/PV for q-tile B (=31-qx, always) and
// q-tile A (=qx, active while i<=qx). vs the old two-pass: 33 -> (32-qx) staged tiles
// (avg 24.5, -26% staging traffic + barriers), and tiles i<=qx carry 2x compute per
// staging round-trip -> prefetch latency hidden independent of TLP. K single-buffered
// (prefetched after the kS-free barrier), V double-buffered. 48 KiB LDS, 3 blocks/CU.
__global__ __launch_bounds__(256, 3) void attn_kernel(
    const ushort* __restrict__ Q, const ushort* __restrict__ K,
    const ushort* __restrict__ Vt, ushort* __restrict__ O)
{
    __shared__ __align__(16) char smem[49152];
    uint4*  kS = (uint4*)smem;                 // [64 s][16 chunks], chunk-swizzled (16 KiB)
    ushort* vS = (ushort*)(smem + 16384);      // 2 x [128 dh][8 slot16], slot ^ (dh&7)

    const int tid = threadIdx.x;
    // XCD swizzle: all 16 q-pair-blocks of head-group g land on xcd = g%8
    const int bid = blockIdx.x;
    const int slot = bid >> 3;
    const int g = (bid & 7) + 8 * (slot >> 4);
    const int qx = slot & 15;
    const int b = g >> 4, h = g & 15;

    const int lane = tid & 63, w = tid >> 6, l15 = lane & 15, quad = lane >> 4;

    const int krow = tid >> 4;                       // 0..15
    const int kchunk = (tid & 15) ^ (krow & 7);
    const ushort* kg = K + ((size_t)(b * T_) + krow) * D_ + h * DH_ + kchunk * 8;

    const int vdh = tid >> 3;                        // 0..31
    const int vslot = (tid & 7) ^ (vdh & 7);
    const ushort* vg = Vt + ((size_t)((b * H_ + h) * DH_) + vdh) * T_ + vslot * 8;
    char* vdst = smem + 16384 + tid * 16;

    const int qtA = qx, qtB = 31 - qx;
    const int nT = qtB + 1;

    // Q B-fragments for both q-tiles (B[k=quad*8+j][n=l15])
    short8 aqA[4], aqB[4];
    {
        const ushort* qpA = Q + ((size_t)(b * T_) + qtA * 64 + w * 16 + l15) * D_ + h * DH_ + quad * 8;
        const ushort* qpB = Q + ((size_t)(b * T_) + qtB * 64 + w * 16 + l15) * D_ + h * DH_ + quad * 8;
#pragma unroll
        for (int ks = 0; ks < 4; ++ks) {
            aqA[ks] = __builtin_bit_cast(short8, *(const uint4*)(qpA + ks * 32));
            aqB[ks] = __builtin_bit_cast(short8, *(const uint4*)(qpB + ks * 32));
        }
    }

    f32x4 accA[8] = {}, accB[8] = {};            // O^T[dh=nt*16+quad*4+r][q=l15]
    float mA = -INFINITY, lA = 0.f;
    float mB = -INFINITY, lB = 0.f;

    // S^T = K Q^T for one q-tile
    auto qkt = [&](short8 (&aq)[4], int stMax, f32x4 (&sT)[4]) {
        __builtin_amdgcn_s_setprio(1);
#pragma unroll
        for (int ks = 0; ks < 4; ++ks)
#pragma unroll
            for (int st = 0; st < 4; ++st)
                if (st < stMax) {
                    int row = st * 16 + l15;
                    short8 ak = __builtin_bit_cast(short8, kS[row * 16 + ((ks * 4 + quad) ^ (row & 7))]);
                    sT[st] = __builtin_amdgcn_mfma_f32_16x16x32_bf16(ak, aq[ks], sT[st], 0, 0, 0);
                }
        __builtin_amdgcn_s_setprio(0);
    };

    // online softmax with defer-max (THR=8 in log2 domain; P bounded by 2^8, f16-safe)
    auto softmax = [&](f32x4 (&sT)[4], int stMax, float& mrow, float& lrow,
                       f32x4 (&accO)[8], half4 (&pb)[4]) {
        float rmax = -INFINITY;
#pragma unroll
        for (int st = 0; st < 4; ++st)
            if (st < stMax)
#pragma unroll
                for (int r = 0; r < 4; ++r) rmax = fmaxf(rmax, sT[st][r]);
        rmax = fmaxf(rmax, __shfl_xor(rmax, 16));
        rmax = fmaxf(rmax, __shfl_xor(rmax, 32));
        if (!__all(rmax <= mrow + 8.0f)) {
            float mnew  = fmaxf(mrow, rmax);
            float alpha = __builtin_amdgcn_exp2f(mrow - mnew);
            mrow = mnew;
            lrow *= alpha;
#pragma unroll
            for (int nt = 0; nt < 8; ++nt)
#pragma unroll
                for (int r = 0; r < 4; ++r) accO[nt][r] *= alpha;
        }
        float psum = 0.f;
#pragma unroll
        for (int st = 0; st < 4; ++st)
            if (st < stMax) {
                float p0 = __builtin_amdgcn_exp2f(sT[st][0] - mrow);
                float p1 = __builtin_amdgcn_exp2f(sT[st][1] - mrow);
                float p2 = __builtin_amdgcn_exp2f(sT[st][2] - mrow);
                float p3 = __builtin_amdgcn_exp2f(sT[st][3] - mrow);
                psum += (p0 + p1) + (p2 + p3);
                uint2 u;
                u.x = __builtin_bit_cast(unsigned int, __builtin_amdgcn_cvt_pkrtz(p0, p1));
                u.y = __builtin_bit_cast(unsigned int, __builtin_amdgcn_cvt_pkrtz(p2, p3));
                pb[st] = __builtin_bit_cast(half4, u);
            }
        psum += __shfl_xor(psum, 16);
        psum += __shfl_xor(psum, 32);
        lrow += psum;
    };

    // O^T += V P^T from swizzled vS buffer
    auto pv = [&](const ushort* vb, half4 (&pb)[4], int stMax, f32x4 (&accO)[8]) {
#pragma unroll
        for (int st = 0; st < 4; ++st)
            if (st < stMax) {
                const int s8 = st * 4 + quad;
                const int off = (((s8 >> 1) ^ (l15 & 7)) << 3) + ((s8 & 1) << 2);
#pragma unroll
                for (int nt = 0; nt < 8; ++nt) {
                    int dh = nt * 16 + l15;
                    half4 vf = *(const half4*)(vb + dh * 64 + off);
                    accO[nt] = __builtin_amdgcn_mfma_f32_16x16x16f16(vf, pb[st], accO[nt], 0, 0, 0);
                }
            }
    };

    // prologue: stage tile 0 (K -> kS, V -> vS buf0)
#pragma unroll
    for (int j = 0; j < 4; ++j) glds16(kg + (size_t)j * 16 * D_, kS + j * 256 + tid);
#pragma unroll
    for (int j = 0; j < 4; ++j) glds16(vg + (size_t)j * 32 * T_, vdst + j * 4096);

    for (int i = 0; i < nT; ++i) {
        const int s0 = i * 64;
        const bool actA = (i <= qtA);
        const int stMaxA = (i == qtA) ? (w + 1) : 4;
        const int stMaxB = (i == qtB) ? (w + 1) : 4;

        __syncthreads();                         // K(i)/V(i) landed (vmcnt0); prev PV done

        half4 pbA[4], pbB[4];
        {
            f32x4 sT[4] = {};
            qkt(aqB, stMaxB, sT);
            if (i == qtB) {                      // B's diagonal tile
                const int q = qtB * 64 + w * 16 + l15;
                const int st = stMaxB - 1;
#pragma unroll
                for (int r = 0; r < 4; ++r)
                    if (s0 + st * 16 + quad * 4 + r > q) sT[st][r] = -INFINITY;
            }
            softmax(sT, stMaxB, mB, lB, accB, pbB);
        }
        if (actA) {
            f32x4 sT[4] = {};
            qkt(aqA, stMaxA, sT);
            if (i == qtA) {                      // A's diagonal tile
                const int q = qtA * 64 + w * 16 + l15;
                const int st = stMaxA - 1;
#pragma unroll
                for (int r = 0; r < 4; ++r)
                    if (s0 + st * 16 + quad * 4 + r > q) sT[st][r] = -INFINITY;
            }
            softmax(sT, stMaxA, mA, lA, accA, pbA);
        }

        __syncthreads();                         // all waves done reading kS

        if (i + 1 < nT) {                        // prefetch tile i+1 under PV
            const ushort* kp = kg + (size_t)(s0 + 64) * D_;
#pragma unroll
            for (int j = 0; j < 4; ++j) glds16(kp + (size_t)j * 16 * D_, kS + j * 256 + tid);
            const ushort* vp = vg + s0 + 64;
            char* vd = vdst + (((i + 1) & 1) << 14);
#pragma unroll
            for (int j = 0; j < 4; ++j) glds16(vp + (size_t)j * 32 * T_, vd + j * 4096);
        }

        const ushort* vb = vS + ((i & 1) << 13);
        __builtin_amdgcn_s_setprio(1);
        pv(vb, pbB, stMaxB, accB);
        if (actA) pv(vb, pbA, stMaxA, accA);
        __builtin_amdgcn_s_setprio(0);
    }

    // epilogue: transpose O^T -> O via wave-private LDS, write bf16 (both q-tiles)
    __syncthreads();                              // all PV reads of vS done (eT overlaps vS)
    ushort* eT = (ushort*)smem + w * 2176;        // [16 q][136 dh-pad]
    auto epi = [&](f32x4 (&accO)[8], float lrow, int q0) {
        float inv = 1.0f / lrow;
#pragma unroll
        for (int nt = 0; nt < 8; ++nt) {
            int dh = nt * 16 + quad * 4;
#pragma unroll
            for (int r = 0; r < 4; ++r)
                eT[l15 * 136 + dh + r] = f2bf(accO[nt][r] * inv);
        }
        for (int idx = lane; idx < 256; idx += 64) {
            int row = idx >> 4, c = idx & 15;
            uint4 v = *(const uint4*)(eT + row * 136 + c * 8);
            *(uint4*)(O + ((size_t)(b * T_) + q0 + w * 16 + row) * D_ + h * DH_ + c * 8) = v;
        }
    };
    epi(accA, lA, qtA * 64);
    epi(accB, lB, qtB * 64);
}

extern "C" void kernel_launch(void* const* d_in, const int* in_sizes, int n_in,
                              void* d_out, int out_size, void* d_ws, size_t ws_size,
                              hipStream_t stream) {
    const float* x  = (const float*)d_in[0];
    const float* Wq = (const float*)d_in[1];
    const float* bq = (const float*)d_in[2];
    const float* Wk = (const float*)d_in[3];
    const float* bk = (const float*)d_in[4];
    const float* Wv = (const float*)d_in[5];
    const float* bv = (const float*)d_in[6];
    const float* Wo = (const float*)d_in[7];
    const float* bo = (const float*)d_in[8];

    char* ws = (char*)d_ws;
    const size_t MB = 1u << 20;
    ushort* xb  = (ushort*)(ws);
    ushort* Wqt = (ushort*)(ws + 32 * MB);
    ushort* Wkt = (ushort*)(ws + 40 * MB);
    ushort* Wvt = (ushort*)(ws + 48 * MB);
    ushort* Wot = (ushort*)(ws + 56 * MB);
    ushort* Qb  = (ushort*)(ws + 64 * MB);
    ushort* Kb  = (ushort*)(ws + 96 * MB);
    ushort* Vtb = (ushort*)(ws + 128 * MB);
    ushort* Ob  = (ushort*)(ws + 160 * MB);

    const int M = B_ * T_;   // 8192
    const float qscale = (float)(0.08838834764831845 * 1.4426950408889634); // 1/sqrt(DH) * log2(e)

    cast_f32_bf16<<<(M * D_) / 1024, 256, 0, stream>>>(x, xb, M * D_);
    dim3 tb(32, 8), tg(D_ / 32, D_ / 32, 4);
    transpose_cast4<<<tg, tb, 0, stream>>>(Wq, Wk, Wv, Wo, Wqt, Wkt, Wvt, Wot);

    gemm_qkv<<<dim3(48, M / 128), 256, 34816, stream>>>(
        xb, Wqt, Wkt, Wvt, bq, bk, bv, Qb, Kb, Vtb, qscale);

    attn_kernel<<<dim3(1024), 256, 0, stream>>>(Qb, Kb, Vtb, Ob);

    gemm_bt_f32<<<dim3(D_ / 128, M / 128), 256, 16384, stream>>>(
        Ob, Wot, bo, (float*)d_out, M, D_, D_);
}

// Round 6
// 639.373 us; speedup vs baseline: 1.5287x; 1.5287x over previous
//
#include <hip/hip_runtime.h>
#include <hip/hip_bf16.h>

#define B_  4
#define T_  2048
#define D_  2048
#define H_  16
#define DH_ 128

typedef __attribute__((ext_vector_type(4))) float f32x4;
typedef __attribute__((ext_vector_type(8))) short short8;
typedef __attribute__((ext_vector_type(4))) _Float16 half4;

__device__ __forceinline__ ushort f2bf(float f) {
    unsigned int u = __builtin_bit_cast(unsigned int, f);
    u += 0x7fffu + ((u >> 16) & 1u);   // RNE
    return (ushort)(u >> 16);
}
__device__ __forceinline__ ushort f2h(float f) {
    return (ushort)(__builtin_bit_cast(unsigned int, __builtin_amdgcn_cvt_pkrtz(f, f)) & 0xffffu);
}

// async global -> LDS, 16B per lane. LDS dst must be wave-uniform base + lane*16.
__device__ __forceinline__ void glds16(const void* g, void* l) {
    __builtin_amdgcn_global_load_lds(
        (const __attribute__((address_space(1))) unsigned int*)g,
        (__attribute__((address_space(3))) unsigned int*)l, 16, 0, 0);
}

// ---------------------------------------------------------------- cast x -> bf16
__global__ void cast_f32_bf16(const float* __restrict__ x, ushort* __restrict__ xb, int n) {
    int i = (blockIdx.x * 256 + threadIdx.x) * 4;
    if (i < n) {
        float4 v = *(const float4*)(x + i);
        ushort4 o;
        o.x = f2bf(v.x); o.y = f2bf(v.y); o.z = f2bf(v.z); o.w = f2bf(v.w);
        *(ushort4*)(xb + i) = o;
    }
}

// ------------------------------------------------- 4x fused: W [k][n] fp32 -> Wt [n][k] bf16
__global__ void transpose_cast4(
    const float* __restrict__ W0, const float* __restrict__ W1,
    const float* __restrict__ W2, const float* __restrict__ W3,
    ushort* __restrict__ T0, ushort* __restrict__ T1,
    ushort* __restrict__ T2, ushort* __restrict__ T3)
{
    const int z = blockIdx.z;
    const float* W = (z == 0) ? W0 : (z == 1) ? W1 : (z == 2) ? W2 : W3;
    ushort* Wt     = (z == 0) ? T0 : (z == 1) ? T1 : (z == 2) ? T2 : T3;
    __shared__ float tile[32][33];
    int tx = threadIdx.x, ty = threadIdx.y;           // 32 x 8
    int n0 = blockIdx.x * 32, k0 = blockIdx.y * 32;
#pragma unroll
    for (int i = 0; i < 4; i++)
        tile[ty + i * 8][tx] = W[(size_t)(k0 + ty + i * 8) * D_ + n0 + tx];
    __syncthreads();
#pragma unroll
    for (int i = 0; i < 4; i++)
        Wt[(size_t)(n0 + ty + i * 8) * D_ + k0 + tx] = f2bf(tile[tx][ty + i * 8]);
}

// ---------------------------------------------------------------- merged QKV GEMM (128^2, proven)
__global__ __launch_bounds__(256, 3) void gemm_qkv(
    const ushort* __restrict__ A,
    const ushort* __restrict__ Wq, const ushort* __restrict__ Wk, const ushort* __restrict__ Wv,
    const float* __restrict__ bq, const float* __restrict__ bk, const float* __restrict__ bv,
    ushort* __restrict__ Qb, ushort* __restrict__ Kb, ushort* __restrict__ Vtb,
    float qscale)
{
    extern __shared__ char smem[];
    uint4* sA = (uint4*)smem;              // [128 rows][4 chunks], slot c holds chunk c^sw(row)
    uint4* sB = (uint4*)(smem + 8192);

    const int tid  = threadIdx.x;
    const int sel  = blockIdx.x >> 4;           // 0=Q 1=K 2=V
    const int row0 = blockIdx.y * 128, col0 = (blockIdx.x & 15) * 128;
    const ushort* Bt = (sel == 0) ? Wq : (sel == 1) ? Wk : Wv;
    const float* bias = (sel == 0) ? bq : (sel == 1) ? bk : bv;
    const float oscale = (sel == 0) ? qscale : 1.0f;
    const int K = D_, N = D_;

    const int mA = tid >> 2, g = tid & 3;
    const int gc = g ^ ((mA >> 2) & 3);
    const ushort* pa0 = A  + (size_t)(row0 + mA) * K + gc * 8;
    const ushort* pb0 = Bt + (size_t)(col0 + mA) * K + gc * 8;

    const int lane = tid & 63, w = tid >> 6;
    const int l15 = lane & 15, quad = lane >> 4;
    const int wm = w & 1, wn = w >> 1;
    const int csel = quad ^ ((l15 >> 2) & 3);
    int aoff[4], boff[4];
#pragma unroll
    for (int mt = 0; mt < 4; mt++) aoff[mt] = (wm * 64 + mt * 16 + l15) * 4 + csel;
#pragma unroll
    for (int nt = 0; nt < 4; nt++) boff[nt] = (wn * 64 + nt * 16 + l15) * 4 + csel;

    f32x4 acc[4][4] = {};

    const int kIter = K >> 5;
    for (int kt = 0; kt < kIter; ++kt) {
        if (kt) __syncthreads();
        glds16(pa0 + kt * 32,                     sA + tid);
        glds16(pa0 + kt * 32 + (size_t)64 * K,    sA + tid + 256);
        glds16(pb0 + kt * 32,                     sB + tid);
        glds16(pb0 + kt * 32 + (size_t)64 * K,    sB + tid + 256);
        __syncthreads();
        short8 af[4], bfr[4];
#pragma unroll
        for (int mt = 0; mt < 4; mt++) af[mt]  = __builtin_bit_cast(short8, sA[aoff[mt]]);
#pragma unroll
        for (int nt = 0; nt < 4; nt++) bfr[nt] = __builtin_bit_cast(short8, sB[boff[nt]]);
#pragma unroll
        for (int mt = 0; mt < 4; mt++)
#pragma unroll
            for (int nt = 0; nt < 4; nt++)
                acc[mt][nt] = __builtin_amdgcn_mfma_f32_16x16x32_bf16(af[mt], bfr[nt], acc[mt][nt], 0, 0, 0);
    }

    if (sel < 2) {
        ushort* Cout = (sel == 0) ? Qb : Kb;
#pragma unroll
        for (int nt = 0; nt < 4; nt++) {
            int col = col0 + wn * 64 + nt * 16 + l15;
            float bb = bias[col];
#pragma unroll
            for (int mt = 0; mt < 4; mt++) {
                int rowb = row0 + wm * 64 + mt * 16 + quad * 4;
#pragma unroll
                for (int r = 0; r < 4; ++r)
                    Cout[(size_t)(rowb + r) * N + col] = f2bf((acc[mt][nt][r] + bb) * oscale);
            }
        }
    } else {
        // V path: transpose 128x128 tile through LDS, emit f16 [B,H,DH,T]
        __syncthreads();
        ushort* tr = (ushort*)smem;        // [128 dh][136]
#pragma unroll
        for (int nt = 0; nt < 4; nt++) {
            int cl = wn * 64 + nt * 16 + l15;
            float bb = bias[col0 + cl];
#pragma unroll
            for (int mt = 0; mt < 4; mt++) {
                int rl = wm * 64 + mt * 16 + quad * 4;
#pragma unroll
                for (int r = 0; r < 4; ++r)
                    tr[cl * 136 + rl + r] = f2h(acc[mt][nt][r] + bb);
            }
        }
        __syncthreads();
        int b = row0 >> 11, t0 = row0 & (T_ - 1), h = col0 >> 7;
        for (int idx = tid; idx < 2048; idx += 256) {
            int dh = idx >> 4, c = idx & 15;
            uint4 v = *(const uint4*)(tr + dh * 136 + c * 8);
            *(uint4*)(Vtb + (size_t)((b * H_ + h) * DH_ + dh) * T_ + t0 + c * 8) = v;
        }
    }
}

// ---------------------------------------------------------------- O-projection GEMM (f32 out, proven)
__global__ __launch_bounds__(256, 3) void gemm_bt_f32(
    const ushort* __restrict__ A, const ushort* __restrict__ Bt,
    const float* __restrict__ bias, float* __restrict__ Cout,
    int M, int N, int K)
{
    extern __shared__ char smem[];
    uint4* sA = (uint4*)smem;
    uint4* sB = (uint4*)(smem + 8192);

    const int tid  = threadIdx.x;
    const int row0 = blockIdx.y * 128, col0 = blockIdx.x * 128;

    const int mA = tid >> 2, g = tid & 3;
    const int gc = g ^ ((mA >> 2) & 3);
    const ushort* pa0 = A  + (size_t)(row0 + mA) * K + gc * 8;
    const ushort* pb0 = Bt + (size_t)(col0 + mA) * K + gc * 8;

    const int lane = tid & 63, w = tid >> 6;
    const int l15 = lane & 15, quad = lane >> 4;
    const int wm = w & 1, wn = w >> 1;
    const int csel = quad ^ ((l15 >> 2) & 3);
    int aoff[4], boff[4];
#pragma unroll
    for (int mt = 0; mt < 4; mt++) aoff[mt] = (wm * 64 + mt * 16 + l15) * 4 + csel;
#pragma unroll
    for (int nt = 0; nt < 4; nt++) boff[nt] = (wn * 64 + nt * 16 + l15) * 4 + csel;

    f32x4 acc[4][4] = {};

    const int kIter = K >> 5;
    for (int kt = 0; kt < kIter; ++kt) {
        if (kt) __syncthreads();
        glds16(pa0 + kt * 32,                     sA + tid);
        glds16(pa0 + kt * 32 + (size_t)64 * K,    sA + tid + 256);
        glds16(pb0 + kt * 32,                     sB + tid);
        glds16(pb0 + kt * 32 + (size_t)64 * K,    sB + tid + 256);
        __syncthreads();
        short8 af[4], bfr[4];
#pragma unroll
        for (int mt = 0; mt < 4; mt++) af[mt]  = __builtin_bit_cast(short8, sA[aoff[mt]]);
#pragma unroll
        for (int nt = 0; nt < 4; nt++) bfr[nt] = __builtin_bit_cast(short8, sB[boff[nt]]);
#pragma unroll
        for (int mt = 0; mt < 4; mt++)
#pragma unroll
            for (int nt = 0; nt < 4; nt++)
                acc[mt][nt] = __builtin_amdgcn_mfma_f32_16x16x32_bf16(af[mt], bfr[nt], acc[mt][nt], 0, 0, 0);
    }

#pragma unroll
    for (int nt = 0; nt < 4; nt++) {
        int col = col0 + wn * 64 + nt * 16 + l15;
        float bb = bias[col];
#pragma unroll
        for (int mt = 0; mt < 4; mt++) {
            int rowb = row0 + wm * 64 + mt * 16 + quad * 4;
#pragma unroll
            for (int r = 0; r < 4; ++r)
                Cout[(size_t)(rowb + r) * N + col] = acc[mt][nt][r] + bb;
        }
    }
}

// ---------------------------------------------------------------- flash attention (S^T / O^T form)
// Q (pre-scaled by 1/sqrt(DH)*log2e), K: [B,T,D] bf16 ; Vt: [B,H,DH,T] f16 ; O: [B,T,D] bf16
// R5: R4's merged two-q-tile pass, but FLATTENED (no lambdas; every array index static)
// and __launch_bounds__(256,2) so the ~160-reg working set allocates without scratch
// (R4's 84-VGPR + 463MB WRITE_SIZE = acc arrays demoted to scratch under the 170 cap).
// Per staged K/V tile i: QK^T/softmax for q-tile B (=31-qx, always) and A (=qx, i<=qx);
// barrier; prefetch K/V(i+1); PV for both. K single-buffered, V double-buffered.
#define QKT_(AQ, STMAX, ST) do {                                                           \
    __builtin_amdgcn_s_setprio(1);                                                         \
    _Pragma("unroll") for (int st = 0; st < 4; ++st)                                       \
      if (st < (STMAX))                                                                    \
        _Pragma("unroll") for (int ks = 0; ks < 4; ++ks) {                                 \
          int row_ = st * 16 + l15;                                                        \
          short8 ak_ = __builtin_bit_cast(short8,                                          \
              kS[row_ * 16 + ((ks * 4 + quad) ^ (row_ & 7))]);                             \
          ST[st] = __builtin_amdgcn_mfma_f32_16x16x32_bf16(ak_, AQ[ks], ST[st], 0, 0, 0);  \
        }                                                                                  \
    __builtin_amdgcn_s_setprio(0);                                                         \
  } while (0)

#define MASK_(QT, STMAX, ST) do {                                                          \
    const int q_ = (QT) * 64 + w * 16 + l15;                                               \
    const int std_ = (STMAX) - 1;                                                          \
    _Pragma("unroll") for (int r = 0; r < 4; ++r)                                          \
      if (s0 + std_ * 16 + quad * 4 + r > q_) ST[std_][r] = -INFINITY;                     \
  } while (0)

#define SM_(ST, STMAX, MR, LR, ACC, PB) do {                                               \
    float rmax_ = -INFINITY;                                                               \
    _Pragma("unroll") for (int st = 0; st < 4; ++st)                                       \
      if (st < (STMAX))                                                                    \
        _Pragma("unroll") for (int r = 0; r < 4; ++r) rmax_ = fmaxf(rmax_, ST[st][r]);     \
    rmax_ = fmaxf(rmax_, __shfl_xor(rmax_, 16));                                           \
    rmax_ = fmaxf(rmax_, __shfl_xor(rmax_, 32));                                           \
    if (!__all(rmax_ <= (MR) + 8.0f)) {                                                   \
      float mnew_ = fmaxf((MR), rmax_);                                                    \
      float al_ = __builtin_amdgcn_exp2f((MR) - mnew_);                                    \
      (MR) = mnew_; (LR) *= al_;                                                           \
      _Pragma("unroll") for (int nt = 0; nt < 8; ++nt)                                     \
        _Pragma("unroll") for (int r = 0; r < 4; ++r) ACC[nt][r] *= al_;                   \
    }                                                                                      \
    float ps_ = 0.f;                                                                       \
    _Pragma("unroll") for (int st = 0; st < 4; ++st)                                       \
      if (st < (STMAX)) {                                                                  \
        float p0_ = __builtin_amdgcn_exp2f(ST[st][0] - (MR));                              \
        float p1_ = __builtin_amdgcn_exp2f(ST[st][1] - (MR));                              \
        float p2_ = __builtin_amdgcn_exp2f(ST[st][2] - (MR));                              \
        float p3_ = __builtin_amdgcn_exp2f(ST[st][3] - (MR));                              \
        ps_ += (p0_ + p1_) + (p2_ + p3_);                                                  \
        uint2 u_;                                                                          \
        u_.x = __builtin_bit_cast(unsigned int, __builtin_amdgcn_cvt_pkrtz(p0_, p1_));     \
        u_.y = __builtin_bit_cast(unsigned int, __builtin_amdgcn_cvt_pkrtz(p2_, p3_));     \
        PB[st] = __builtin_bit_cast(half4, u_);                                            \
      }                                                                                    \
    ps_ += __shfl_xor(ps_, 16);                                                            \
    ps_ += __shfl_xor(ps_, 32);                                                            \
    (LR) += ps_;                                                                           \
  } while (0)

#define PV_(VB, PB, STMAX, ACC) do {                                                       \
    _Pragma("unroll") for (int st = 0; st < 4; ++st)                                       \
      if (st < (STMAX)) {                                                                  \
        const int s8_ = st * 4 + quad;                                                     \
        const int off_ = (((s8_ >> 1) ^ (l15 & 7)) << 3) + ((s8_ & 1) << 2);               \
        _Pragma("unroll") for (int nt = 0; nt < 8; ++nt) {                                 \
          int dh_ = nt * 16 + l15;                                                         \
          half4 vf_ = *(const half4*)((VB) + dh_ * 64 + off_);                             \
          ACC[nt] = __builtin_amdgcn_mfma_f32_16x16x16f16(vf_, PB[st], ACC[nt], 0, 0, 0);  \
        }                                                                                  \
      }                                                                                    \
  } while (0)

#define EPI_(ACC, LR, Q0) do {                                                             \
    float inv_ = 1.0f / (LR);                                                              \
    _Pragma("unroll") for (int nt = 0; nt < 8; ++nt) {                                     \
      int dh_ = nt * 16 + quad * 4;                                                        \
      _Pragma("unroll") for (int r = 0; r < 4; ++r)                                        \
        eT[l15 * 136 + dh_ + r] = f2bf(ACC[nt][r] * inv_);                                 \
    }                                                                                      \
    for (int idx = lane; idx < 256; idx += 64) {                                           \
      int row_ = idx >> 4, c_ = idx & 15;                                                  \
      uint4 v_ = *(const uint4*)(eT + row_ * 136 + c_ * 8);                                \
      *(uint4*)(O + ((size_t)(b * T_) + (Q0) + w * 16 + row_) * D_ + h * DH_ + c_ * 8) = v_; \
    }                                                                                      \
  } while (0)

__global__ __launch_bounds__(256, 2) void attn_kernel(
    const ushort* __restrict__ Q, const ushort* __restrict__ K,
    const ushort* __restrict__ Vt, ushort* __restrict__ O)
{
    __shared__ __align__(16) char smem[49152];
    uint4*  kS = (uint4*)smem;                 // [64 s][16 chunks], chunk-swizzled (16 KiB)
    ushort* vS = (ushort*)(smem + 16384);      // 2 x [128 dh][8 slot16], slot ^ (dh&7)

    const int tid = threadIdx.x;
    const int bid = blockIdx.x;
    const int slot = bid >> 3;
    const int g = (bid & 7) + 8 * (slot >> 4);
    const int qx = slot & 15;
    const int b = g >> 4, h = g & 15;

    const int lane = tid & 63, w = tid >> 6, l15 = lane & 15, quad = lane >> 4;

    const int krow = tid >> 4;                       // 0..15
    const int kchunk = (tid & 15) ^ (krow & 7);
    const ushort* kg = K + ((size_t)(b * T_) + krow) * D_ + h * DH_ + kchunk * 8;

    const int vdh = tid >> 3;                        // 0..31
    const int vslot = (tid & 7) ^ (vdh & 7);
    const ushort* vg = Vt + ((size_t)((b * H_ + h) * DH_) + vdh) * T_ + vslot * 8;
    char* vdst = smem + 16384 + tid * 16;

    const int qtA = qx, qtB = 31 - qx;
    const int nT = qtB + 1;

    // Q B-fragments for both q-tiles (B[k=quad*8+j][n=l15])
    short8 aqA[4], aqB[4];
    {
        const ushort* qpA = Q + ((size_t)(b * T_) + qtA * 64 + w * 16 + l15) * D_ + h * DH_ + quad * 8;
        const ushort* qpB = Q + ((size_t)(b * T_) + qtB * 64 + w * 16 + l15) * D_ + h * DH_ + quad * 8;
#pragma unroll
        for (int ks = 0; ks < 4; ++ks) {
            aqA[ks] = __builtin_bit_cast(short8, *(const uint4*)(qpA + ks * 32));
            aqB[ks] = __builtin_bit_cast(short8, *(const uint4*)(qpB + ks * 32));
        }
    }

    f32x4 accA[8] = {}, accB[8] = {};            // O^T[dh=nt*16+quad*4+r][q=l15]
    float mAx = -INFINITY, lAx = 0.f;
    float mBx = -INFINITY, lBx = 0.f;

    // prologue: stage tile 0 (K -> kS, V -> vS buf0)
#pragma unroll
    for (int j = 0; j < 4; ++j) glds16(kg + (size_t)j * 16 * D_, kS + j * 256 + tid);
#pragma unroll
    for (int j = 0; j < 4; ++j) glds16(vg + (size_t)j * 32 * T_, vdst + j * 4096);

    for (int i = 0; i < nT; ++i) {
        const int s0 = i * 64;
        const bool actA = (i <= qtA);
        const int stMaxA = (i == qtA) ? (w + 1) : 4;
        const int stMaxB = (i == qtB) ? (w + 1) : 4;

        __syncthreads();                         // K(i)/V(i) landed (vmcnt0); prev PV done

        half4 pbA[4], pbB[4];
        {
            f32x4 sT[4];
            sT[0] = (f32x4)(0.f); sT[1] = (f32x4)(0.f); sT[2] = (f32x4)(0.f); sT[3] = (f32x4)(0.f);
            QKT_(aqB, stMaxB, sT);
            if (i == qtB) MASK_(qtB, stMaxB, sT);
            SM_(sT, stMaxB, mBx, lBx, accB, pbB);
        }
        if (actA) {
            f32x4 sT[4];
            sT[0] = (f32x4)(0.f); sT[1] = (f32x4)(0.f); sT[2] = (f32x4)(0.f); sT[3] = (f32x4)(0.f);
            QKT_(aqA, stMaxA, sT);
            if (i == qtA) MASK_(qtA, stMaxA, sT);
            SM_(sT, stMaxA, mAx, lAx, accA, pbA);
        }

        __syncthreads();                         // all waves done reading kS

        if (i + 1 < nT) {                        // prefetch tile i+1 under PV
            const ushort* kp = kg + (size_t)(s0 + 64) * D_;
#pragma unroll
            for (int j = 0; j < 4; ++j) glds16(kp + (size_t)j * 16 * D_, kS + j * 256 + tid);
            const ushort* vp = vg + s0 + 64;
            char* vd = vdst + (((i + 1) & 1) << 14);
#pragma unroll
            for (int j = 0; j < 4; ++j) glds16(vp + (size_t)j * 32 * T_, vd + j * 4096);
        }

        const ushort* vb = vS + ((i & 1) << 13);
        __builtin_amdgcn_s_setprio(1);
        PV_(vb, pbB, stMaxB, accB);
        if (actA) PV_(vb, pbA, stMaxA, accA);
        __builtin_amdgcn_s_setprio(0);
    }

    // epilogue: transpose O^T -> O via wave-private LDS, write bf16 (both q-tiles)
    __syncthreads();                              // all PV reads of vS done (w3's eT tail overlaps vS)
    ushort* eT = (ushort*)smem + w * 2176;        // [16 q][136 dh-pad]
    EPI_(accA, lAx, qtA * 64);
    EPI_(accB, lBx, qtB * 64);
}

extern "C" void kernel_launch(void* const* d_in, const int* in_sizes, int n_in,
                              void* d_out, int out_size, void* d_ws, size_t ws_size,
                              hipStream_t stream) {
    const float* x  = (const float*)d_in[0];
    const float* Wq = (const float*)d_in[1];
    const float* bq = (const float*)d_in[2];
    const float* Wk = (const float*)d_in[3];
    const float* bk = (const float*)d_in[4];
    const float* Wv = (const float*)d_in[5];
    const float* bv = (const float*)d_in[6];
    const float* Wo = (const float*)d_in[7];
    const float* bo = (const float*)d_in[8];

    char* ws = (char*)d_ws;
    const size_t MB = 1u << 20;
    ushort* xb  = (ushort*)(ws);
    ushort* Wqt = (ushort*)(ws + 32 * MB);
    ushort* Wkt = (ushort*)(ws + 40 * MB);
    ushort* Wvt = (ushort*)(ws + 48 * MB);
    ushort* Wot = (ushort*)(ws + 56 * MB);
    ushort* Qb  = (ushort*)(ws + 64 * MB);
    ushort* Kb  = (ushort*)(ws + 96 * MB);
    ushort* Vtb = (ushort*)(ws + 128 * MB);
    ushort* Ob  = (ushort*)(ws + 160 * MB);

    const int M = B_ * T_;   // 8192
    const float qscale = (float)(0.08838834764831845 * 1.4426950408889634); // 1/sqrt(DH) * log2(e)

    cast_f32_bf16<<<(M * D_) / 1024, 256, 0, stream>>>(x, xb, M * D_);
    dim3 tb(32, 8), tg(D_ / 32, D_ / 32, 4);
    transpose_cast4<<<tg, tb, 0, stream>>>(Wq, Wk, Wv, Wo, Wqt, Wkt, Wvt, Wot);

    gemm_qkv<<<dim3(48, M / 128), 256, 34816, stream>>>(
        xb, Wqt, Wkt, Wvt, bq, bk, bv, Qb, Kb, Vtb, qscale);

    attn_kernel<<<dim3(1024), 256, 0, stream>>>(Qb, Kb, Vtb, Ob);

    gemm_bt_f32<<<dim3(D_ / 128, M / 128), 256, 16384, stream>>>(
        Ob, Wot, bo, (float*)d_out, M, D_, D_);
}